// Round 10
// baseline (105.133 us; speedup 1.0000x reference)
//
#include <hip/hip_runtime.h>
#include <hip/hip_bf16.h>

typedef __bf16 bf16x8 __attribute__((ext_vector_type(8)));
typedef float  f32x4  __attribute__((ext_vector_type(4)));
typedef short  short8 __attribute__((ext_vector_type(8)));
typedef unsigned int u32;

#define KDE_IGNORE (-100)
#define NSL  16       // N slices (2 per XCD)
#define GBM  128      // m rows per block (wave tile 64m x 32n)
#define GBN  64       // n cols per n-tile
#define BK   128      // k per phase (2 phases over K=256)
#define GD   256
#define NSLOT (NSL * 2)

__device__ __forceinline__ f32x4 mfma16x16(bf16x8 a, bf16x8 b, f32x4 c) {
  return __builtin_amdgcn_mfma_f32_16x16x32_bf16(a, b, c, 0, 0, 0);
}

// async 16B/lane global->LDS (LDS dest = wave-uniform base + lane*16)
__device__ __forceinline__ void gload_lds16(const short* g, short* l) {
  __builtin_amdgcn_global_load_lds(
      (const __attribute__((address_space(1))) u32*)g,
      (__attribute__((address_space(3))) u32*)l, 16, 0, 0);
}

// volatile 16B load as bf16x8: compiler cannot rematerialize (re-execute) it,
// so the loaded values stay pinned in VGPRs (or spill, which FETCH would show).
__device__ __forceinline__ bf16x8 vload_bf16x8(const short* p) {
  union { int v[4]; bf16x8 b; } u;
  const volatile int* q = reinterpret_cast<const volatile int*>(p);
  u.v[0] = q[0]; u.v[1] = q[1]; u.v[2] = q[2]; u.v[3] = q[3];
  return u.b;
}

// convert 8 fp32 -> 8 bf16
__device__ __forceinline__ bf16x8 cvt8b(const float* p) {
  float4 a = *reinterpret_cast<const float4*>(p);
  float4 b = *reinterpret_cast<const float4*>(p + 4);
  union { bf16x8 v; __bf16 h[8]; } u;
  u.h[0] = (__bf16)a.x; u.h[1] = (__bf16)a.y; u.h[2] = (__bf16)a.z; u.h[3] = (__bf16)a.w;
  u.h[4] = (__bf16)b.x; u.h[5] = (__bf16)b.y; u.h[6] = (__bf16)b.z; u.h[7] = (__bf16)b.w;
  return u.v;
}
__device__ __forceinline__ short8 cvt8s(const float* p) {
  union { bf16x8 b; short8 s; } u; u.b = cvt8b(p); return u.s;
}

// ---- Kernel 1 (merged prep):
// blocks [0, N/8): supp rows -> sn (fp32 exact) + PRE-SWIZZLED bf16 suppB
//   (row r, k-half h, logical chunk j stored at (h*16 + (j^(r&15)))*8 shorts)
// blocks [N/8, N/8+M/8): pred rows -> LINEAR bf16 predB (no norm; pn cancels)
template<bool CONV>
__global__ void prep_kernel(const float* __restrict__ supp, const float* __restrict__ pred,
                            float* __restrict__ sn, short* __restrict__ suppB,
                            short* __restrict__ predB, int N, int M) {
  const int nbS = N >> 3;
  const int b = blockIdx.x;
  const int sub = ((threadIdx.x >> 6) << 1) + ((threadIdx.x & 63) >> 5);
  const int c = threadIdx.x & 31;           // logical 16B chunk 0..31
  if (b < nbS) {
    int row = b * 8 + sub;
    const float* src = supp + (size_t)row * GD + c * 8;
    float4 a = *reinterpret_cast<const float4*>(src);
    float4 v = *reinterpret_cast<const float4*>(src + 4);
    if (CONV) {
      union { short8 s8; __bf16 h[8]; } u;
      u.h[0] = (__bf16)a.x; u.h[1] = (__bf16)a.y; u.h[2] = (__bf16)a.z; u.h[3] = (__bf16)a.w;
      u.h[4] = (__bf16)v.x; u.h[5] = (__bf16)v.y; u.h[6] = (__bf16)v.z; u.h[7] = (__bf16)v.w;
      int h = c >> 4, j = c & 15;
      int pos = h * 16 + (j ^ (row & 15));
      *reinterpret_cast<short8*>(suppB + (size_t)row * GD + pos * 8) = u.s8;
    }
    float s = a.x*a.x + a.y*a.y + a.z*a.z + a.w*a.w
            + v.x*v.x + v.y*v.y + v.z*v.z + v.w*v.w;
#pragma unroll
    for (int off = 16; off >= 1; off >>= 1) s += __shfl_xor(s, off, 32);
    if (c == 0) sn[row] = s;
  } else if (CONV) {
    int row = (b - nbS) * 8 + sub;
    if (row < M) {
      const float* src = pred + (size_t)row * GD + c * 8;
      *reinterpret_cast<short8*>(predB + (size_t)row * GD + c * 8) = cvt8s(src);
    }
  }
}

// ---- Kernel 2: fused GEMM + exp + masked row-accumulate, atomic-free.
// 256 thr = 4 waves (2m x 2n); block 128m x 64n per n-tile, K phased 2x128.
// A (pred bf16) full-K PINNED in registers (volatile loads, 128 VGPR);
// B half-tiles double-buffered in LDS via global_load_lds (pre-swizzled src).
// launch_bounds(256,2): cap 256 >= demand ~232 -> no spill. Grid 512 = 2/CU.
template<bool PRE>
__global__ __launch_bounds__(256, 2)
void kde_gemm_kernel(const float* __restrict__ pred, const float* __restrict__ suppF,
                     const short* __restrict__ suppB, const short* __restrict__ predB,
                     const int* __restrict__ tgt, const int* __restrict__ suppT,
                     const float* __restrict__ sn,
                     float* __restrict__ denomP, float* __restrict__ numerP,
                     int M, int N) {
  __shared__ __align__(16) short Bs[2][GBN * BK];   // 2 x 16 KiB

  const int bid = blockIdx.x;
  const int mb  = bid >> 4;           // 0..M/128-1
  const int s   = bid & 15;           // slice; XCD = bid & 7
  const int m0  = mb * GBM;
  const int nslice = N >> 4;          // 1024
  const int nbase  = s * nslice;
  const int ntile  = nslice / GBN;    // 16 n-tiles (2 phases each)
  const int t    = threadIdx.x;
  const int lane = t & 63;
  const int wid  = t >> 6;            // 0..3
  const int wm   = (wid >> 1) * 64;   // wave m-offset (64 rows)
  const int wng  = wid & 1;
  const int wnl  = wng * 32;
  const int lr = lane >> 4, lc = lane & 15;

  // per-lane global offset (shorts) within a 4-row staging group
  const int gvoff = (lane >> 4) * GD + (lane & 15) * 8;

  // ---- A fragments: full K=256 pinned in registers (bf16).
  bf16x8 af[4][8];
  if (PRE) {
    const short* abase = predB + (size_t)(m0 + wm + lc) * GD + lr * 8;
#pragma unroll
    for (int mt = 0; mt < 4; ++mt)
#pragma unroll
      for (int kk = 0; kk < 8; ++kk)
        af[mt][kk] = vload_bf16x8(abase + mt * 16 * GD + kk * 32);
  } else {
    const float* abaseF = pred + (size_t)(m0 + wm + lc) * GD + lr * 8;
#pragma unroll
    for (int mt = 0; mt < 4; ++mt)
#pragma unroll
      for (int kk = 0; kk < 8; ++kk)
        af[mt][kk] = cvt8b(abaseF + mt * 16 * GD + kk * 32);
  }
  int tmv[4][4];
#pragma unroll
  for (int mt = 0; mt < 4; ++mt)
#pragma unroll
    for (int rg = 0; rg < 4; ++rg)
      tmv[mt][rg] = tgt[m0 + wm + mt * 16 + lr * 4 + rg];

  float dac[4][4] = {}, nac[4][4] = {};

  const float SC  = 1.4426950408889634f / 128.0f;   // log2e/128 (for 2*dot)
  const float SCH = 1.4426950408889634f / 256.0f;   // log2e/256 (for sn)

  // ---- stage (tile 0, k-half 0) into Bs[0]
  if (PRE) {
#pragma unroll
    for (int i = 0; i < 4; ++i) {
      int rowbase = wid * 16 + i * 4;
      gload_lds16(suppB + (size_t)(nbase + rowbase) * GD + gvoff, &Bs[0][rowbase * BK]);
    }
  } else {
#pragma unroll
    for (int i = 0; i < 4; ++i) {
      int C = i * 256 + t; int row = C >> 4; int j = C & 15;
      short8 v = cvt8s(suppF + (size_t)(nbase + row) * GD + j * 8);
      *reinterpret_cast<short8*>(&Bs[0][row * BK + ((j ^ (row & 15)) << 3)]) = v;
    }
  }
  __syncthreads();

  f32x4 acc[4][2] = {};
  float snv[2]; int stv[2];
#pragma unroll
  for (int nt = 0; nt < 2; ++nt) {
    int j = nbase + wnl + nt * 16 + lc;
    snv[nt] = sn[j]; stv[nt] = suppT[j];
  }

  for (int it = 0; it < ntile; ++it) {
    const int n0 = nbase + it * GBN;
    const bool more = (it + 1 < ntile);

    // ======== phase 0: stage (it, kh=1) -> Bs[1]; compute k-half 0 from Bs[0]
    short8 sreg[4];
    if (PRE) {
#pragma unroll
      for (int i = 0; i < 4; ++i) {
        int rowbase = wid * 16 + i * 4;
        gload_lds16(suppB + (size_t)(n0 + rowbase) * GD + BK + gvoff, &Bs[1][rowbase * BK]);
      }
    } else {
#pragma unroll
      for (int i = 0; i < 4; ++i) {
        int C = i * 256 + t; int row = C >> 4; int j = C & 15;
        sreg[i] = cvt8s(suppF + (size_t)(n0 + row) * GD + BK + j * 8);
      }
    }
    __builtin_amdgcn_s_setprio(1);
#pragma unroll
    for (int ks = 0; ks < 4; ++ks) {
      bf16x8 bfr[2];
#pragma unroll
      for (int nt = 0; nt < 2; ++nt) {
        int r = wnl + nt * 16 + lc;
        int cs = (ks * 4 + lr) ^ (r & 15);
        bfr[nt] = *reinterpret_cast<const bf16x8*>(&Bs[0][r * BK + (cs << 3)]);
      }
#pragma unroll
      for (int mt = 0; mt < 4; ++mt)
#pragma unroll
        for (int nt = 0; nt < 2; ++nt)
          acc[mt][nt] = mfma16x16(af[mt][ks], bfr[nt], acc[mt][nt]);
    }
    __builtin_amdgcn_s_setprio(0);
    if (!PRE) {
#pragma unroll
      for (int i = 0; i < 4; ++i) {
        int C = i * 256 + t; int row = C >> 4; int j = C & 15;
        *reinterpret_cast<short8*>(&Bs[1][row * BK + ((j ^ (row & 15)) << 3)]) = sreg[i];
      }
    }
    __syncthreads();

    // ======== phase 1: stage (it+1, kh=0) -> Bs[0]; compute k-half 1 from Bs[1]
    if (more) {
      if (PRE) {
#pragma unroll
        for (int i = 0; i < 4; ++i) {
          int rowbase = wid * 16 + i * 4;
          gload_lds16(suppB + (size_t)(n0 + GBN + rowbase) * GD + gvoff, &Bs[0][rowbase * BK]);
        }
      } else {
#pragma unroll
        for (int i = 0; i < 4; ++i) {
          int C = i * 256 + t; int row = C >> 4; int j = C & 15;
          sreg[i] = cvt8s(suppF + (size_t)(n0 + GBN + row) * GD + j * 8);
        }
      }
    }
    __builtin_amdgcn_s_setprio(1);
#pragma unroll
    for (int ks = 0; ks < 4; ++ks) {
      bf16x8 bfr[2];
#pragma unroll
      for (int nt = 0; nt < 2; ++nt) {
        int r = wnl + nt * 16 + lc;
        int cs = (ks * 4 + lr) ^ (r & 15);
        bfr[nt] = *reinterpret_cast<const bf16x8*>(&Bs[1][r * BK + (cs << 3)]);
      }
#pragma unroll
      for (int mt = 0; mt < 4; ++mt)
#pragma unroll
        for (int nt = 0; nt < 2; ++nt)
          acc[mt][nt] = mfma16x16(af[mt][4 + ks], bfr[nt], acc[mt][nt]);
    }
    __builtin_amdgcn_s_setprio(0);
    if (!PRE && more) {
#pragma unroll
      for (int i = 0; i < 4; ++i) {
        int C = i * 256 + t; int row = C >> 4; int j = C & 15;
        *reinterpret_cast<short8*>(&Bs[0][row * BK + ((j ^ (row & 15)) << 3)]) = sreg[i];
      }
    }

    // ---- n-tile epilogue: e = 2^((2c - sn)*log2e/256); pn cancels in ratio
#pragma unroll
    for (int nt = 0; nt < 2; ++nt) {
      float sh = -snv[nt] * SCH;
#pragma unroll
      for (int mt = 0; mt < 4; ++mt)
#pragma unroll
        for (int rg = 0; rg < 4; ++rg) {
          float e = exp2f(fmaf(acc[mt][nt][rg], SC, sh));
          dac[mt][rg] += e;
          nac[mt][rg] += (stv[nt] == tmv[mt][rg]) ? e : 0.0f;
        }
    }
#pragma unroll
    for (int mt = 0; mt < 4; ++mt)
#pragma unroll
      for (int nt = 0; nt < 2; ++nt) acc[mt][nt] = f32x4{0.f, 0.f, 0.f, 0.f};
    if (more) {
      const int nn0 = n0 + GBN;
#pragma unroll
      for (int nt = 0; nt < 2; ++nt) {
        int j = nn0 + wnl + nt * 16 + lc;
        snv[nt] = sn[j]; stv[nt] = suppT[j];
      }
    }
    __syncthreads();
  }

  // reduce over the 16 lanes (lc) sharing each m, write slot partials
#pragma unroll
  for (int off = 1; off < 16; off <<= 1) {
#pragma unroll
    for (int mt = 0; mt < 4; ++mt)
#pragma unroll
      for (int rg = 0; rg < 4; ++rg) {
        dac[mt][rg] += __shfl_xor(dac[mt][rg], off);
        nac[mt][rg] += __shfl_xor(nac[mt][rg], off);
      }
  }
  if (lc == 0) {
    const int slot = s * 2 + wng;           // 32 slots per m
#pragma unroll
    for (int mt = 0; mt < 4; ++mt)
#pragma unroll
      for (int rg = 0; rg < 4; ++rg) {
        int m = m0 + wm + mt * 16 + lr * 4 + rg;
        denomP[(size_t)slot * M + m] = dac[mt][rg];
        numerP[(size_t)slot * M + m] = nac[mt][rg];
      }
  }
}

// ---- Kernel 3: per-m sum over 32 slots -> nll, per-block partial sums
__global__ void kde_reduce_kernel(const float* __restrict__ denomP, const float* __restrict__ numerP,
                                  const int* __restrict__ tgt,
                                  float* __restrict__ bsum, float* __restrict__ bcnt, int M) {
  __shared__ float sS[4], sC[4];
  int m = blockIdx.x * 256 + threadIdx.x;
  float den = 0.0f, num = 0.0f;
#pragma unroll
  for (int sl = 0; sl < NSLOT; ++sl) {
    den += denomP[(size_t)sl * M + m];
    num += numerP[(size_t)sl * M + m];
  }
  int tg = tgt[m];
  bool valid = (tg != KDE_IGNORE);
  float p = fmaxf(num / fmaxf(den, 1e-10f), 1e-10f);
  float nll = valid ? -logf(p) : 0.0f;
  float cnt = valid ? 1.0f : 0.0f;
#pragma unroll
  for (int off = 32; off >= 1; off >>= 1) {
    nll += __shfl_xor(nll, off);
    cnt += __shfl_xor(cnt, off);
  }
  int wid = threadIdx.x >> 6, lane = threadIdx.x & 63;
  if (lane == 0) { sS[wid] = nll; sC[wid] = cnt; }
  __syncthreads();
  if (threadIdx.x == 0) {
    bsum[blockIdx.x] = sS[0] + sS[1] + sS[2] + sS[3];
    bcnt[blockIdx.x] = sC[0] + sC[1] + sC[2] + sC[3];
  }
}

__global__ void kde_final_kernel(const float* __restrict__ bsum, const float* __restrict__ bcnt,
                                 float* __restrict__ out, int nb) {
  int tid = threadIdx.x;
  float s = (tid < nb) ? bsum[tid] : 0.0f;
  float c = (tid < nb) ? bcnt[tid] : 0.0f;
#pragma unroll
  for (int off = 32; off >= 1; off >>= 1) {
    s += __shfl_xor(s, off);
    c += __shfl_xor(c, off);
  }
  if (tid == 0) out[0] = s / fmaxf(c, 1.0f);
}

extern "C" void kernel_launch(void* const* d_in, const int* in_sizes, int n_in,
                              void* d_out, int out_size, void* d_ws, size_t ws_size,
                              hipStream_t stream) {
  const float* supp  = (const float*)d_in[0];   // (N, 256)
  const float* pred  = (const float*)d_in[1];   // (M, 256)
  const int*   suppT = (const int*)d_in[2];     // (N,)
  const int*   tgt   = (const int*)d_in[3];     // (M,)
  const int N = in_sizes[2];
  const int M = in_sizes[3];

  float* sn     = (float*)d_ws;                      // N
  float* denomP = sn + N;                            // NSLOT*M
  float* numerP = denomP + (size_t)NSLOT * M;        // NSLOT*M
  float* bsum   = numerP + (size_t)NSLOT * M;        // M/256
  float* bcnt   = bsum + 16;                         // M/256
  short* suppB  = (short*)(bcnt + 16);               // N*256 bf16 (pre-swizzled)
  short* predB  = suppB + (size_t)N * GD;            // M*256 bf16 (linear)

  size_t small = sizeof(float) * ((size_t)N + 2 * (size_t)NSLOT * M + 32);
  bool pre = ws_size >= small + sizeof(short) * (size_t)(N + M) * GD;

  if (pre) prep_kernel<true ><<<dim3(N / 8 + M / 8), dim3(256), 0, stream>>>(supp, pred, sn, suppB, predB, N, M);
  else     prep_kernel<false><<<dim3(N / 8), dim3(256), 0, stream>>>(supp, pred, sn, nullptr, nullptr, N, M);

  dim3 grid((M / GBM) * NSL);   // 512 blocks; XCD = bid & 7; 2 blocks/CU exact
  if (pre) kde_gemm_kernel<true ><<<grid, dim3(256), 0, stream>>>(
      pred, supp, suppB, predB, tgt, suppT, sn, denomP, numerP, M, N);
  else     kde_gemm_kernel<false><<<grid, dim3(256), 0, stream>>>(
      pred, supp, suppB, predB, tgt, suppT, sn, denomP, numerP, M, N);

  kde_reduce_kernel<<<dim3(M / 256), dim3(256), 0, stream>>>(denomP, numerP, tgt, bsum, bcnt, M);
  kde_final_kernel<<<dim3(1), dim3(64), 0, stream>>>(bsum, bcnt, (float*)d_out, M / 256);
}

// Round 11
// 96.539 us; speedup vs baseline: 1.0890x; 1.0890x over previous
//
#include <hip/hip_runtime.h>
#include <hip/hip_bf16.h>

typedef __bf16 bf16x8 __attribute__((ext_vector_type(8)));
typedef float  f32x4  __attribute__((ext_vector_type(4)));
typedef short  short8 __attribute__((ext_vector_type(8)));
typedef unsigned int u32;

#define KDE_IGNORE (-100)
#define NSL  16       // N slices (2 per XCD)
#define GBM  64       // m rows per block
#define GBN  64       // n cols per n-tile
#define BK   128      // k per phase (2 phases over K=256)
#define GD   256
#define NSLOT (NSL * 2)

__device__ __forceinline__ f32x4 mfma16x16(bf16x8 a, bf16x8 b, f32x4 c) {
  return __builtin_amdgcn_mfma_f32_16x16x32_bf16(a, b, c, 0, 0, 0);
}

// async 16B/lane global->LDS (LDS dest = wave-uniform base + lane*16)
__device__ __forceinline__ void gload_lds16(const short* g, short* l) {
  __builtin_amdgcn_global_load_lds(
      (const __attribute__((address_space(1))) u32*)g,
      (__attribute__((address_space(3))) u32*)l, 16, 0, 0);
}

// convert 8 fp32 -> 8 bf16
__device__ __forceinline__ bf16x8 cvt8b(const float* p) {
  float4 a = *reinterpret_cast<const float4*>(p);
  float4 b = *reinterpret_cast<const float4*>(p + 4);
  union { bf16x8 v; __bf16 h[8]; } u;
  u.h[0] = (__bf16)a.x; u.h[1] = (__bf16)a.y; u.h[2] = (__bf16)a.z; u.h[3] = (__bf16)a.w;
  u.h[4] = (__bf16)b.x; u.h[5] = (__bf16)b.y; u.h[6] = (__bf16)b.z; u.h[7] = (__bf16)b.w;
  return u.v;
}
__device__ __forceinline__ short8 cvt8s(const float* p) {
  union { bf16x8 b; short8 s; } u; u.b = cvt8b(p); return u.s;
}

// ---- Kernel 1 (merged prep):
// blocks [0, N/8): supp rows -> sn (fp32 exact) + PRE-SWIZZLED bf16 suppB
//   (row r, k-half h, logical chunk j stored at (h*16 + (j^(r&15)))*8 shorts)
// blocks [N/8, ...): pred rows -> LINEAR bf16 predB (pn cancels in the ratio)
template<bool CONV>
__global__ void prep_kernel(const float* __restrict__ supp, const float* __restrict__ pred,
                            float* __restrict__ sn, short* __restrict__ suppB,
                            short* __restrict__ predB, int N, int M) {
  const int nbS = N >> 3;
  const int b = blockIdx.x;
  const int sub = ((threadIdx.x >> 6) << 1) + ((threadIdx.x & 63) >> 5);
  const int c = threadIdx.x & 31;           // logical 16B chunk 0..31
  if (b < nbS) {
    int row = b * 8 + sub;
    const float* src = supp + (size_t)row * GD + c * 8;
    float4 a = *reinterpret_cast<const float4*>(src);
    float4 v = *reinterpret_cast<const float4*>(src + 4);
    if (CONV) {
      union { short8 s8; __bf16 h[8]; } u;
      u.h[0] = (__bf16)a.x; u.h[1] = (__bf16)a.y; u.h[2] = (__bf16)a.z; u.h[3] = (__bf16)a.w;
      u.h[4] = (__bf16)v.x; u.h[5] = (__bf16)v.y; u.h[6] = (__bf16)v.z; u.h[7] = (__bf16)v.w;
      int h = c >> 4, j = c & 15;
      int pos = h * 16 + (j ^ (row & 15));
      *reinterpret_cast<short8*>(suppB + (size_t)row * GD + pos * 8) = u.s8;
    }
    float s = a.x*a.x + a.y*a.y + a.z*a.z + a.w*a.w
            + v.x*v.x + v.y*v.y + v.z*v.z + v.w*v.w;
#pragma unroll
    for (int off = 16; off >= 1; off >>= 1) s += __shfl_xor(s, off, 32);
    if (c == 0) sn[row] = s;
  } else if (CONV) {
    int row = (b - nbS) * 8 + sub;
    if (row < M) {
      const float* src = pred + (size_t)row * GD + c * 8;
      *reinterpret_cast<short8*>(predB + (size_t)row * GD + c * 8) = cvt8s(src);
    }
  }
}

// ---- Kernel 2: fused GEMM + exp + masked row-accumulate, atomic-free.
// 256 thr = 4 waves (2m x 2n); block 64m x 64n per n-tile, K phased 2x128.
// A full-K in regs; B staged via global_load_lds into a 3-buffer LDS rotation
// with COUNTED vmcnt waits + raw s_barrier: prefetched loads stay in flight
// across barriers (no vmcnt(0) drain in the main loop).
template<bool PRE>
__global__ __launch_bounds__(256, 3)
void kde_gemm_kernel(const float* __restrict__ pred, const float* __restrict__ suppF,
                     const short* __restrict__ suppB, const short* __restrict__ predB,
                     const int* __restrict__ tgt, const int* __restrict__ suppT,
                     const float* __restrict__ sn,
                     float* __restrict__ denomP, float* __restrict__ numerP,
                     int M, int N) {
  __shared__ __align__(16) short Bs[3][GBN * BK];   // 3 x 16 KiB

  const int bid = blockIdx.x;
  const int mb  = bid >> 4;           // 0..M/64-1
  const int s   = bid & 15;           // slice; XCD = bid & 7
  const int m0  = mb * GBM;
  const int nslice = N >> 4;          // 1024
  const int nbase  = s * nslice;
  const int nphase = (nslice / GBN) * 2;   // 32 phases (16 n-tiles x 2 k-halves)
  const int t    = threadIdx.x;
  const int lane = t & 63;
  const int wid  = t >> 6;            // 0..3
  const int wm   = (wid >> 1) * 32;
  const int wng  = wid & 1;
  const int wnl  = wng * 32;
  const int lr = lane >> 4, lc = lane & 15;

  // per-lane global offset (shorts) within a 4-row staging group
  const int gvoff = (lane >> 4) * GD + (lane & 15) * 8;

  // ---- A fragments: full K=256 in registers (bf16).
  bf16x8 af[2][8];
  if (PRE) {
    const short* abase = predB + (size_t)(m0 + wm + lc) * GD + lr * 8;
#pragma unroll
    for (int mt = 0; mt < 2; ++mt)
#pragma unroll
      for (int kk = 0; kk < 8; ++kk)
        af[mt][kk] = *reinterpret_cast<const bf16x8*>(abase + mt * 16 * GD + kk * 32);
  } else {
    const float* abaseF = pred + (size_t)(m0 + wm + lc) * GD + lr * 8;
#pragma unroll
    for (int mt = 0; mt < 2; ++mt)
#pragma unroll
      for (int kk = 0; kk < 8; ++kk)
        af[mt][kk] = cvt8b(abaseF + mt * 16 * GD + kk * 32);
  }
  int tmv[2][4];
#pragma unroll
  for (int mt = 0; mt < 2; ++mt)
#pragma unroll
    for (int rg = 0; rg < 4; ++rg)
      tmv[mt][rg] = tgt[m0 + wm + mt * 16 + lr * 4 + rg];

  float dac[2][4] = {}, nac[2][4] = {};

  const float SC  = 1.4426950408889634f / 128.0f;   // log2e/128 (for 2*dot)
  const float SCH = 1.4426950408889634f / 256.0f;   // log2e/256 (for sn)

  // ---- stage phase 0 (tile 0, kh 0) into buf 0
  if (PRE) {
#pragma unroll
    for (int i = 0; i < 4; ++i) {
      int rowbase = wid * 16 + i * 4;
      gload_lds16(suppB + (size_t)(nbase + rowbase) * GD + gvoff, &Bs[0][rowbase * BK]);
    }
  } else {
#pragma unroll
    for (int i = 0; i < 4; ++i) {
      int C = i * 256 + t; int row = C >> 4; int j = C & 15;
      short8 v = cvt8s(suppF + (size_t)(nbase + row) * GD + j * 8);
      *reinterpret_cast<short8*>(&Bs[0][row * BK + ((j ^ (row & 15)) << 3)]) = v;
    }
    __syncthreads();
  }

  f32x4 acc[2][2] = {};
  float snv[2]; int stv[2];
#pragma unroll
  for (int nt = 0; nt < 2; ++nt) {
    int j = nbase + wnl + nt * 16 + lc;
    snv[nt] = sn[j]; stv[nt] = suppT[j];
  }

  int cur = 0, nxt = 1;
  for (int ph = 0; ph < nphase; ++ph) {
    const int p = ph & 1;               // k-half of current phase
    const bool more = (ph + 1 < nphase);

    // ---- issue next phase's staging into buf nxt (stays in flight past barrier)
    short8 sreg[4];  // !PRE only
    if (more) {
      const int q = ph + 1;
      const int qn0 = nbase + (q >> 1) * GBN;
      const int qko = (q & 1) * BK;
      if (PRE) {
#pragma unroll
        for (int i = 0; i < 4; ++i) {
          int rowbase = wid * 16 + i * 4;
          gload_lds16(suppB + (size_t)(qn0 + rowbase) * GD + qko + gvoff, &Bs[nxt][rowbase * BK]);
        }
      } else {
#pragma unroll
        for (int i = 0; i < 4; ++i) {
          int C = i * 256 + t; int row = C >> 4; int j = C & 15;
          sreg[i] = cvt8s(suppF + (size_t)(qn0 + row) * GD + qko + j * 8);
        }
      }
    }

    // ---- counted wait: current tile's 4 loads done, next tile's 4 still flying
    if (PRE) {
      if (more) asm volatile("s_waitcnt vmcnt(4)" ::: "memory");
      else      asm volatile("s_waitcnt vmcnt(0)" ::: "memory");
      __builtin_amdgcn_s_barrier();
      __builtin_amdgcn_sched_barrier(0);
    }

    // ---- MFMA: 16 per wave from buf cur
    __builtin_amdgcn_s_setprio(1);
#pragma unroll
    for (int ks = 0; ks < 4; ++ks) {
      bf16x8 bfr[2];
#pragma unroll
      for (int nt = 0; nt < 2; ++nt) {
        int r = wnl + nt * 16 + lc;
        int cs = (ks * 4 + lr) ^ (r & 15);
        bfr[nt] = *reinterpret_cast<const bf16x8*>(&Bs[cur][r * BK + (cs << 3)]);
      }
      if (p == 0) {
#pragma unroll
        for (int mt = 0; mt < 2; ++mt)
#pragma unroll
          for (int nt = 0; nt < 2; ++nt)
            acc[mt][nt] = mfma16x16(af[mt][ks], bfr[nt], acc[mt][nt]);
      } else {
#pragma unroll
        for (int mt = 0; mt < 2; ++mt)
#pragma unroll
          for (int nt = 0; nt < 2; ++nt)
            acc[mt][nt] = mfma16x16(af[mt][4 + ks], bfr[nt], acc[mt][nt]);
      }
    }
    __builtin_amdgcn_s_setprio(0);

    if (!PRE) {
      // reg-staged write-late into buf nxt, then full-drain barrier
      if (more) {
#pragma unroll
        for (int i = 0; i < 4; ++i) {
          int C = i * 256 + t; int row = C >> 4; int j = C & 15;
          *reinterpret_cast<short8*>(&Bs[nxt][row * BK + ((j ^ (row & 15)) << 3)]) = sreg[i];
        }
      }
      __syncthreads();
    }

    // ---- n-tile complete at odd phase: fused epilogue
    if (p == 1) {
#pragma unroll
      for (int nt = 0; nt < 2; ++nt) {
        float sh = -snv[nt] * SCH;
#pragma unroll
        for (int mt = 0; mt < 2; ++mt)
#pragma unroll
          for (int rg = 0; rg < 4; ++rg) {
            float e = exp2f(fmaf(acc[mt][nt][rg], SC, sh));
            dac[mt][rg] += e;
            nac[mt][rg] += (stv[nt] == tmv[mt][rg]) ? e : 0.0f;
          }
      }
#pragma unroll
      for (int mt = 0; mt < 2; ++mt)
#pragma unroll
        for (int nt = 0; nt < 2; ++nt) acc[mt][nt] = f32x4{0.f, 0.f, 0.f, 0.f};
      if (more) {
        const int nn0 = nbase + ((ph + 1) >> 1) * GBN;
#pragma unroll
        for (int nt = 0; nt < 2; ++nt) {
          int j = nn0 + wnl + nt * 16 + lc;
          snv[nt] = sn[j]; stv[nt] = suppT[j];
        }
      }
    }

    cur = nxt; nxt = (nxt == 2) ? 0 : nxt + 1;
  }

  // reduce over the 16 lanes (lc) sharing each m, write slot partials
#pragma unroll
  for (int off = 1; off < 16; off <<= 1) {
#pragma unroll
    for (int mt = 0; mt < 2; ++mt)
#pragma unroll
      for (int rg = 0; rg < 4; ++rg) {
        dac[mt][rg] += __shfl_xor(dac[mt][rg], off);
        nac[mt][rg] += __shfl_xor(nac[mt][rg], off);
      }
  }
  if (lc == 0) {
    const int slot = s * 2 + wng;           // 32 slots per m
#pragma unroll
    for (int mt = 0; mt < 2; ++mt)
#pragma unroll
      for (int rg = 0; rg < 4; ++rg) {
        int m = m0 + wm + mt * 16 + lr * 4 + rg;
        denomP[(size_t)slot * M + m] = dac[mt][rg];
        numerP[(size_t)slot * M + m] = nac[mt][rg];
      }
  }
}

// ---- Kernel 3: per-m sum over 32 slots -> nll, per-block partial sums
__global__ void kde_reduce_kernel(const float* __restrict__ denomP, const float* __restrict__ numerP,
                                  const int* __restrict__ tgt,
                                  float* __restrict__ bsum, float* __restrict__ bcnt, int M) {
  __shared__ float sS[4], sC[4];
  int m = blockIdx.x * 256 + threadIdx.x;
  float den = 0.0f, num = 0.0f;
#pragma unroll
  for (int sl = 0; sl < NSLOT; ++sl) {
    den += denomP[(size_t)sl * M + m];
    num += numerP[(size_t)sl * M + m];
  }
  int tg = tgt[m];
  bool valid = (tg != KDE_IGNORE);
  float p = fmaxf(num / fmaxf(den, 1e-10f), 1e-10f);
  float nll = valid ? -logf(p) : 0.0f;
  float cnt = valid ? 1.0f : 0.0f;
#pragma unroll
  for (int off = 32; off >= 1; off >>= 1) {
    nll += __shfl_xor(nll, off);
    cnt += __shfl_xor(cnt, off);
  }
  int wid = threadIdx.x >> 6, lane = threadIdx.x & 63;
  if (lane == 0) { sS[wid] = nll; sC[wid] = cnt; }
  __syncthreads();
  if (threadIdx.x == 0) {
    bsum[blockIdx.x] = sS[0] + sS[1] + sS[2] + sS[3];
    bcnt[blockIdx.x] = sC[0] + sC[1] + sC[2] + sC[3];
  }
}

__global__ void kde_final_kernel(const float* __restrict__ bsum, const float* __restrict__ bcnt,
                                 float* __restrict__ out, int nb) {
  int tid = threadIdx.x;
  float s = (tid < nb) ? bsum[tid] : 0.0f;
  float c = (tid < nb) ? bcnt[tid] : 0.0f;
#pragma unroll
  for (int off = 32; off >= 1; off >>= 1) {
    s += __shfl_xor(s, off);
    c += __shfl_xor(c, off);
  }
  if (tid == 0) out[0] = s / fmaxf(c, 1.0f);
}

extern "C" void kernel_launch(void* const* d_in, const int* in_sizes, int n_in,
                              void* d_out, int out_size, void* d_ws, size_t ws_size,
                              hipStream_t stream) {
  const float* supp  = (const float*)d_in[0];   // (N, 256)
  const float* pred  = (const float*)d_in[1];   // (M, 256)
  const int*   suppT = (const int*)d_in[2];     // (N,)
  const int*   tgt   = (const int*)d_in[3];     // (M,)
  const int N = in_sizes[2];
  const int M = in_sizes[3];

  float* sn     = (float*)d_ws;                      // N
  float* denomP = sn + N;                            // NSLOT*M
  float* numerP = denomP + (size_t)NSLOT * M;        // NSLOT*M
  float* bsum   = numerP + (size_t)NSLOT * M;        // M/256
  float* bcnt   = bsum + 16;                         // M/256
  short* suppB  = (short*)(bcnt + 16);               // N*256 bf16 (pre-swizzled)
  short* predB  = suppB + (size_t)N * GD;            // M*256 bf16 (linear)

  size_t small = sizeof(float) * ((size_t)N + 2 * (size_t)NSLOT * M + 32);
  bool pre = ws_size >= small + sizeof(short) * (size_t)(N + M) * GD;

  if (pre) prep_kernel<true ><<<dim3(N / 8 + M / 8), dim3(256), 0, stream>>>(supp, pred, sn, suppB, predB, N, M);
  else     prep_kernel<false><<<dim3(N / 8), dim3(256), 0, stream>>>(supp, pred, sn, nullptr, nullptr, N, M);

  dim3 grid((M / GBM) * NSL);   // 1024 blocks; XCD = bid & 7
  if (pre) kde_gemm_kernel<true ><<<grid, dim3(256), 0, stream>>>(
      pred, supp, suppB, predB, tgt, suppT, sn, denomP, numerP, M, N);
  else     kde_gemm_kernel<false><<<grid, dim3(256), 0, stream>>>(
      pred, supp, suppB, predB, tgt, suppT, sn, denomP, numerP, M, N);

  kde_reduce_kernel<<<dim3(M / 256), dim3(256), 0, stream>>>(denomP, numerP, tgt, bsum, bcnt, M);
  kde_final_kernel<<<dim3(1), dim3(64), 0, stream>>>(bsum, bcnt, (float*)d_out, M / 256);
}